// Round 1
// baseline (1289.872 us; speedup 1.0000x reference)
//
#include <hip/hip_runtime.h>

// SupContrastive loss, simplified:
//   loss_i = log1p( (sum_j exp(p_ij) - exp(p_it)) * exp(-p_it) ),  t = y_true[i]
//   out    = mean_i loss_i
// B=8192 rows, C=32000 cols. Memory-bound: 1.05 GB read -> ~166 us floor @6.3TB/s.

#define B_ROWS 8192
#define C_COLS 32000
#define BLOCK  256

__global__ __launch_bounds__(BLOCK) void row_loss_kernel(
        const float* __restrict__ y_pred,
        const int* __restrict__ y_true,
        float* __restrict__ row_loss) {
    const int row = blockIdx.x;
    const float* __restrict__ p = y_pred + (size_t)row * C_COLS;
    const int tid = threadIdx.x;

    // C_COLS = 32000 = 8000 float4; 256 threads -> 31.25 vec-iters each.
    const float4* __restrict__ p4 = (const float4*)p;
    float s = 0.0f;
    for (int j = tid; j < C_COLS / 4; j += BLOCK) {
        float4 v = p4[j];
        s += __expf(v.x) + __expf(v.y) + __expf(v.z) + __expf(v.w);
    }

    // wave (64-lane) shuffle reduction
    #pragma unroll
    for (int off = 32; off > 0; off >>= 1) s += __shfl_down(s, off, 64);

    __shared__ float wsum[BLOCK / 64];
    const int lane = tid & 63, wave = tid >> 6;
    if (lane == 0) wsum[wave] = s;
    __syncthreads();

    if (tid == 0) {
        float tot = wsum[0] + wsum[1] + wsum[2] + wsum[3];
        const int t = y_true[row];
        const float pt = p[t];
        const float et = __expf(pt);
        const float x = (tot - et) * __expf(-pt);
        row_loss[row] = log1pf(x);
    }
}

__global__ __launch_bounds__(BLOCK) void final_reduce_kernel(
        const float* __restrict__ row_loss,
        float* __restrict__ out) {
    const int tid = threadIdx.x;
    float s = 0.0f;
    for (int j = tid; j < B_ROWS; j += BLOCK) s += row_loss[j];

    #pragma unroll
    for (int off = 32; off > 0; off >>= 1) s += __shfl_down(s, off, 64);

    __shared__ float wsum[BLOCK / 64];
    const int lane = tid & 63, wave = tid >> 6;
    if (lane == 0) wsum[wave] = s;
    __syncthreads();

    if (tid == 0) {
        out[0] = (wsum[0] + wsum[1] + wsum[2] + wsum[3]) / (float)B_ROWS;
    }
}

extern "C" void kernel_launch(void* const* d_in, const int* in_sizes, int n_in,
                              void* d_out, int out_size, void* d_ws, size_t ws_size,
                              hipStream_t stream) {
    const float* y_pred = (const float*)d_in[0];
    const int*   y_true = (const int*)d_in[1];   // harness passes integers as int32
    float* out = (float*)d_out;
    float* row_loss = (float*)d_ws;              // 8192 floats = 32 KB scratch

    row_loss_kernel<<<B_ROWS, BLOCK, 0, stream>>>(y_pred, y_true, row_loss);
    final_reduce_kernel<<<1, BLOCK, 0, stream>>>(row_loss, out);
}